// Round 1
// baseline (260.911 us; speedup 1.0000x reference)
//
#include <hip/hip_runtime.h>
#include <cstdint>
#include <cstddef>

// Problem constants
#define B_   2
#define S_   2048
#define D_   1024
#define H_   16
#define DH_  64
#define NROW (B_ * S_)   // 4096 rows for all projection GEMMs

typedef __bf16  bf16x8 __attribute__((ext_vector_type(8)));
typedef __bf16  bf16x4 __attribute__((ext_vector_type(4)));
typedef float   f32x4  __attribute__((ext_vector_type(4)));

#define MFMA16(a, b, c) __builtin_amdgcn_mfma_f32_16x16x32_bf16((a), (b), (c), 0, 0, 0)

// async global->LDS, 16B per lane. LDS dest must be wave-uniform base + lane*16
// (we always pass lane-contiguous pointers so readfirstlane(base) is correct).
__device__ __forceinline__ void gload_lds16(const void* g, void* l) {
  __builtin_amdgcn_global_load_lds(
      (__attribute__((address_space(1))) void*)(g),
      (__attribute__((address_space(3))) void*)(l), 16, 0, 0);
}

// ---------------------------------------------------------------------------
// fp32 -> bf16 cast, 4 elems/thread
__global__ void cast_f32_bf16(const float* __restrict__ src,
                              __bf16* __restrict__ dst, int n4) {
  int i = blockIdx.x * blockDim.x + threadIdx.x;
  if (i < n4) {
    float4 v = ((const float4*)src)[i];
    bf16x4 o;
    o[0] = (__bf16)v.x; o[1] = (__bf16)v.y; o[2] = (__bf16)v.z; o[3] = (__bf16)v.w;
    ((bf16x4*)dst)[i] = o;
  }
}

// ---------------------------------------------------------------------------
// C[n,m] = sum_k A[n,k] * W[m,k] + bias[m]   (torch Linear: x @ W.T + b)
// A:[N,K] bf16 row-major, W:[M,K] bf16 row-major. 128x128 tile, BK=32,
// 256 thr = 4 waves in 2x2, each wave owns 4x4 16x16 MFMA subtiles.
template <int C_BF16>
__global__ __launch_bounds__(256, 2) void gemm_bt_bias(
    const __bf16* __restrict__ A, const __bf16* __restrict__ W,
    const float* __restrict__ bias, void* __restrict__ C,
    int N, int M, int K) {
  __shared__ __bf16 As[128 * 32];   // 8 KB
  __shared__ __bf16 Bs[128 * 32];   // 8 KB
  const int tid  = threadIdx.x;
  const int lane = tid & 63, wave = tid >> 6;
  const int lo   = lane & 15, quad = lane >> 4;
  const int wr   = wave & 1,  wc   = wave >> 1;
  const int bn   = blockIdx.x, bm = blockIdx.y;
  const __bf16* Ag = A + (size_t)bn * 128 * K;
  const __bf16* Wg = W + (size_t)bm * 128 * K;
  // staging: 512 chunks of 16B per 8KB tile; thread stages chunks tid, tid+256
  const int c0 = tid, c1 = tid + 256;
  const int r0 = c0 >> 2, s0 = (c0 & 3) * 8;
  const int r1 = c1 >> 2, s1 = (c1 & 3) * 8;

  f32x4 acc[4][4] = {};
  for (int k0 = 0; k0 < K; k0 += 32) {
    __syncthreads();  // protect LDS from prior-iteration readers
    gload_lds16(Ag + (size_t)r0 * K + k0 + s0, &As[c0 * 8]);
    gload_lds16(Ag + (size_t)r1 * K + k0 + s1, &As[c1 * 8]);
    gload_lds16(Wg + (size_t)r0 * K + k0 + s0, &Bs[c0 * 8]);
    gload_lds16(Wg + (size_t)r1 * K + k0 + s1, &Bs[c1 * 8]);
    __syncthreads();  // drains vmcnt -> LDS filled
    bf16x8 af[4], bfr[4];
#pragma unroll
    for (int i = 0; i < 4; i++)
      af[i] = *(const bf16x8*)&As[(wr * 64 + i * 16 + lo) * 32 + quad * 8];
#pragma unroll
    for (int j = 0; j < 4; j++)
      bfr[j] = *(const bf16x8*)&Bs[(wc * 64 + j * 16 + lo) * 32 + quad * 8];
#pragma unroll
    for (int i = 0; i < 4; i++)
#pragma unroll
      for (int j = 0; j < 4; j++)
        acc[i][j] = MFMA16(af[i], bfr[j], acc[i][j]);
  }
  // epilogue: D row = quad*4+reg, col = lane&15
#pragma unroll
  for (int i = 0; i < 4; i++) {
    const int row = bn * 128 + wr * 64 + i * 16 + quad * 4;
#pragma unroll
    for (int j = 0; j < 4; j++) {
      const int col = bm * 128 + wc * 64 + j * 16 + lo;
      const float bv = bias[col];
#pragma unroll
      for (int r = 0; r < 4; r++) {
        float v = acc[i][j][r] + bv;
        if (C_BF16) ((__bf16*)C)[(size_t)(row + r) * M + col] = (__bf16)v;
        else        ((float*)C)[(size_t)(row + r) * M + col] = v;
      }
    }
  }
}

// ---------------------------------------------------------------------------
// Sliding-window causal attention. Block = (q-tile of 64, head, batch),
// 4 waves, wave owns 16 queries. 5 key-tiles of 64 cover the 256-window.
// Single-pass softmax: all 5*4 score subtiles (80 f32/lane) held in VGPRs.
__global__ __launch_bounds__(256, 2) void attn_win(
    const __bf16* __restrict__ Qp, const __bf16* __restrict__ Kp,
    const __bf16* __restrict__ Vp, __bf16* __restrict__ ctx) {
  const int qt = blockIdx.x, h = blockIdx.y, b = blockIdx.z;
  const int q0 = qt * 64;
  // stride 88 elems = 176B: 16B-aligned and only 2-way LDS bank aliasing
  __shared__ __bf16 Vt[64 * 88];       // V tile transposed: Vt[d][j]
  __shared__ __bf16 Pb[4][16 * 88];    // per-wave P in A-layout staging
  const int tid = threadIdx.x, wave = tid >> 6, lane = tid & 63;
  const int lo = lane & 15, quad = lane >> 4;
  const size_t base = ((size_t)b * S_) * D_ + (size_t)h * DH_;

  // Q fragments (A-operand: m=lo, k=quad*8+j), d split 0..31 / 32..63
  const int qrow = q0 + wave * 16 + lo;
  const bf16x8 qf0 = *(const bf16x8*)&Qp[base + (size_t)qrow * D_ + quad * 8];
  const bf16x8 qf1 = *(const bf16x8*)&Qp[base + (size_t)qrow * D_ + 32 + quad * 8];

  // ---- scores: S[q, k] = sum_d Q[q,d] K[k,d]  (B^T form, K rows direct) ----
  f32x4 sc[5][4];
#pragma unroll
  for (int t = 0; t < 5; t++) {
    const int k0 = q0 - 256 + t * 64;
#pragma unroll
    for (int kt = 0; kt < 4; kt++) {
      int krow = k0 + kt * 16 + lo;
      if (krow < 0) krow = 0;  // clamped; masked below
      const bf16x8 kf0 = *(const bf16x8*)&Kp[base + (size_t)krow * D_ + quad * 8];
      const bf16x8 kf1 = *(const bf16x8*)&Kp[base + (size_t)krow * D_ + 32 + quad * 8];
      f32x4 c = {0.f, 0.f, 0.f, 0.f};
      c = MFMA16(qf0, kf0, c);
      c = MFMA16(qf1, kf1, c);
      sc[t][kt] = c;
    }
  }

  // ---- mask + softmax (C-layout: q = quad*4+r, k = tile + kt*16 + lo) ----
  const float scale = 0.125f;  // 64^-0.5
  float mrow[4] = {-3e38f, -3e38f, -3e38f, -3e38f};
#pragma unroll
  for (int t = 0; t < 5; t++) {
    const int k0 = q0 - 256 + t * 64;
#pragma unroll
    for (int kt = 0; kt < 4; kt++) {
      const int kg = k0 + kt * 16 + lo;
#pragma unroll
      for (int r = 0; r < 4; r++) {
        const int qg = q0 + wave * 16 + quad * 4 + r;
        const bool keep = (kg >= 0) && (kg <= qg) && (kg > qg - 256);
        const float v = keep ? sc[t][kt][r] * scale : -3e38f;
        sc[t][kt][r] = v;
        mrow[r] = fmaxf(mrow[r], v);
      }
    }
  }
#pragma unroll
  for (int r = 0; r < 4; r++)
#pragma unroll
    for (int off = 1; off < 16; off <<= 1)
      mrow[r] = fmaxf(mrow[r], __shfl_xor(mrow[r], off));

  float lrow[4] = {0.f, 0.f, 0.f, 0.f};
#pragma unroll
  for (int t = 0; t < 5; t++)
#pragma unroll
    for (int kt = 0; kt < 4; kt++)
#pragma unroll
      for (int r = 0; r < 4; r++) {
        const float p = __expf(sc[t][kt][r] - mrow[r]);
        sc[t][kt][r] = p;
        lrow[r] += p;
      }
#pragma unroll
  for (int r = 0; r < 4; r++)
#pragma unroll
    for (int off = 1; off < 16; off <<= 1)
      lrow[r] += __shfl_xor(lrow[r], off);

  // ---- O = P V over valid key tiles ----
  f32x4 oacc[4] = {};
  const int tmin = (q0 >= 256) ? 0 : (256 - q0) / 64;  // uniform per block
#pragma unroll
  for (int t = 0; t < 5; t++) {
    if (t < tmin) continue;
    const int k0 = q0 - 256 + t * 64;
    __syncthreads();  // protect Vt/Pb from prior-iteration readers
    {  // stage V transposed: Vt[d][j] = V[k0+j][d]; coalesced 32B row reads
      const int j = tid >> 2, dbase = (tid & 3) * 16;
      int vrow = k0 + j;
      if (vrow < 0) vrow = 0;  // P=0 there, any finite value ok
      const __bf16* vsrc = &Vp[base + (size_t)vrow * D_ + dbase];
      const bf16x8 vv0 = *(const bf16x8*)&vsrc[0];
      const bf16x8 vv1 = *(const bf16x8*)&vsrc[8];
#pragma unroll
      for (int i = 0; i < 8; i++) Vt[(dbase + i) * 88 + j] = vv0[i];
#pragma unroll
      for (int i = 0; i < 8; i++) Vt[(dbase + 8 + i) * 88 + j] = vv1[i];
    }
    // write this tile's P from C-layout regs into A-layout LDS (per-wave)
#pragma unroll
    for (int kt = 0; kt < 4; kt++)
#pragma unroll
      for (int r = 0; r < 4; r++)
        Pb[wave][(quad * 4 + r) * 88 + kt * 16 + lo] = (__bf16)sc[t][kt][r];
    __syncthreads();
    const bf16x8 pf0 = *(const bf16x8*)&Pb[wave][lo * 88 + quad * 8];
    const bf16x8 pf1 = *(const bf16x8*)&Pb[wave][lo * 88 + 32 + quad * 8];
#pragma unroll
    for (int ds = 0; ds < 4; ds++) {
      const bf16x8 vf0 = *(const bf16x8*)&Vt[(ds * 16 + lo) * 88 + quad * 8];
      const bf16x8 vf1 = *(const bf16x8*)&Vt[(ds * 16 + lo) * 88 + 32 + quad * 8];
      oacc[ds] = MFMA16(pf0, vf0, oacc[ds]);
      oacc[ds] = MFMA16(pf1, vf1, oacc[ds]);
    }
  }

  // ---- write ctx[b*S+q][h*64+d] = O/l ----
#pragma unroll
  for (int ds = 0; ds < 4; ds++)
#pragma unroll
    for (int r = 0; r < 4; r++) {
      const int qg = q0 + wave * 16 + quad * 4 + r;
      ctx[base + (size_t)qg * D_ + ds * 16 + lo] = (__bf16)(oacc[ds][r] / lrow[r]);
    }
}

// ---------------------------------------------------------------------------
extern "C" void kernel_launch(void* const* d_in, const int* in_sizes, int n_in,
                              void* d_out, int out_size, void* d_ws, size_t ws_size,
                              hipStream_t stream) {
  (void)in_sizes; (void)n_in; (void)out_size; (void)ws_size;
  const float* q_in = (const float*)d_in[0];
  const float* k_in = (const float*)d_in[1];
  const float* v_in = (const float*)d_in[2];
  const float* Wq   = (const float*)d_in[3];
  const float* bq   = (const float*)d_in[4];
  const float* Wk   = (const float*)d_in[5];
  const float* bk   = (const float*)d_in[6];
  const float* Wv   = (const float*)d_in[7];
  const float* bv   = (const float*)d_in[8];
  const float* Wo   = (const float*)d_in[9];
  const float* bo   = (const float*)d_in[10];

  const size_t XN = (size_t)NROW * D_;  // 4M elems
  const size_t WN = (size_t)D_ * D_;    // 1M elems
  char* ws = (char*)d_ws;               // total 64 MB used
  __bf16* xq  = (__bf16*)ws; ws += XN * 2;
  __bf16* xk  = (__bf16*)ws; ws += XN * 2;
  __bf16* xv  = (__bf16*)ws; ws += XN * 2;
  __bf16* wqb = (__bf16*)ws; ws += WN * 2;
  __bf16* wkb = (__bf16*)ws; ws += WN * 2;
  __bf16* wvb = (__bf16*)ws; ws += WN * 2;
  __bf16* wob = (__bf16*)ws; ws += WN * 2;
  __bf16* Qp  = (__bf16*)ws; ws += XN * 2;
  __bf16* Kp  = (__bf16*)ws; ws += XN * 2;
  __bf16* Vp  = (__bf16*)ws; ws += XN * 2;
  __bf16* ctx = (__bf16*)ws; ws += XN * 2;

  const int thr = 256;
  cast_f32_bf16<<<(int)(XN / 4 / thr), thr, 0, stream>>>(q_in, xq, (int)(XN / 4));
  cast_f32_bf16<<<(int)(XN / 4 / thr), thr, 0, stream>>>(k_in, xk, (int)(XN / 4));
  cast_f32_bf16<<<(int)(XN / 4 / thr), thr, 0, stream>>>(v_in, xv, (int)(XN / 4));
  cast_f32_bf16<<<(int)(WN / 4 / thr), thr, 0, stream>>>(Wq, wqb, (int)(WN / 4));
  cast_f32_bf16<<<(int)(WN / 4 / thr), thr, 0, stream>>>(Wk, wkb, (int)(WN / 4));
  cast_f32_bf16<<<(int)(WN / 4 / thr), thr, 0, stream>>>(Wv, wvb, (int)(WN / 4));
  cast_f32_bf16<<<(int)(WN / 4 / thr), thr, 0, stream>>>(Wo, wob, (int)(WN / 4));

  dim3 gg(NROW / 128, D_ / 128);  // 32 x 8
  gemm_bt_bias<1><<<gg, 256, 0, stream>>>(xq, wqb, bq, Qp, NROW, D_, D_);
  gemm_bt_bias<1><<<gg, 256, 0, stream>>>(xk, wkb, bk, Kp, NROW, D_, D_);
  gemm_bt_bias<1><<<gg, 256, 0, stream>>>(xv, wvb, bv, Vp, NROW, D_, D_);

  dim3 ga(S_ / 64, H_, B_);  // 32 x 16 x 2
  attn_win<<<ga, 256, 0, stream>>>(Qp, Kp, Vp, ctx);

  gemm_bt_bias<0><<<gg, 256, 0, stream>>>(ctx, wob, bo, d_out, NROW, D_, D_);
}

// Round 2
// 198.412 us; speedup vs baseline: 1.3150x; 1.3150x over previous
//
#include <hip/hip_runtime.h>
#include <cstdint>
#include <cstddef>

// Problem constants
#define B_   2
#define S_   2048
#define D_   1024
#define H_   16
#define DH_  64
#define NROW (B_ * S_)   // 4096 rows for all projection GEMMs

typedef __bf16  bf16x8 __attribute__((ext_vector_type(8)));
typedef __bf16  bf16x4 __attribute__((ext_vector_type(4)));
typedef float   f32x4  __attribute__((ext_vector_type(4)));

#define MFMA16(a, b, c) __builtin_amdgcn_mfma_f32_16x16x32_bf16((a), (b), (c), 0, 0, 0)

__device__ __forceinline__ void gload_lds16(const void* g, void* l) {
  __builtin_amdgcn_global_load_lds(
      (__attribute__((address_space(1))) void*)(g),
      (__attribute__((address_space(3))) void*)(l), 16, 0, 0);
}

// ---------------------------------------------------------------------------
// fused casts: 3 X inputs (1M float4-groups each), 4 W inputs (256K each)
struct Ptr3 { const float* p[3]; };
struct Ptr4 { const float* p[4]; };

__global__ void cast3(Ptr3 src, __bf16* dst, int n4each) {
  const int i = blockIdx.x * blockDim.x + threadIdx.x;
  const float4 v = ((const float4*)src.p[blockIdx.y])[i];
  bf16x4 o; o[0] = (__bf16)v.x; o[1] = (__bf16)v.y; o[2] = (__bf16)v.z; o[3] = (__bf16)v.w;
  ((bf16x4*)dst)[(size_t)blockIdx.y * n4each + i] = o;
}
__global__ void cast4(Ptr4 src, __bf16* dst, int n4each) {
  const int i = blockIdx.x * blockDim.x + threadIdx.x;
  const float4 v = ((const float4*)src.p[blockIdx.y])[i];
  bf16x4 o; o[0] = (__bf16)v.x; o[1] = (__bf16)v.y; o[2] = (__bf16)v.z; o[3] = (__bf16)v.w;
  ((bf16x4*)dst)[(size_t)blockIdx.y * n4each + i] = o;
}

// ---------------------------------------------------------------------------
// Fused QKV projection: blockIdx.z picks (A,W,bias,C). 128x128 tile, BK=32.
// z==2 (V) writes transposed Vt[b][h][d][s] so attention's B-operand staging
// is row-contiguous; z<2 writes natural [row][col].
struct QKVArgs {
  const __bf16* A[3]; const __bf16* W[3]; const float* bias[3]; __bf16* C[3];
};

__global__ __launch_bounds__(256, 2) void gemm_qkv(QKVArgs args) {
  __shared__ __bf16 As[128 * 32];
  __shared__ __bf16 Bs[128 * 32];
  const int z = blockIdx.z;
  const __bf16* A = args.A[z];
  const __bf16* W = args.W[z];
  const float* bias = args.bias[z];
  __bf16* C = args.C[z];
  const int tid  = threadIdx.x;
  const int lane = tid & 63, wave = tid >> 6;
  const int lo   = lane & 15, quad = lane >> 4;
  const int wr   = wave & 1,  wc   = wave >> 1;
  const int bn   = blockIdx.x, bm = blockIdx.y;
  const __bf16* Ag = A + (size_t)bn * 128 * D_;
  const __bf16* Wg = W + (size_t)bm * 128 * D_;
  const int c0 = tid, c1 = tid + 256;
  const int r0 = c0 >> 2, s0 = (c0 & 3) * 8;
  const int r1 = c1 >> 2, s1 = (c1 & 3) * 8;

  f32x4 acc[4][4] = {};
  for (int k0 = 0; k0 < D_; k0 += 32) {
    __syncthreads();
    gload_lds16(Ag + (size_t)r0 * D_ + k0 + s0, &As[c0 * 8]);
    gload_lds16(Ag + (size_t)r1 * D_ + k0 + s1, &As[c1 * 8]);
    gload_lds16(Wg + (size_t)r0 * D_ + k0 + s0, &Bs[c0 * 8]);
    gload_lds16(Wg + (size_t)r1 * D_ + k0 + s1, &Bs[c1 * 8]);
    __syncthreads();
    bf16x8 af[4], bfr[4];
#pragma unroll
    for (int i = 0; i < 4; i++)
      af[i] = *(const bf16x8*)&As[(wr * 64 + i * 16 + lo) * 32 + quad * 8];
#pragma unroll
    for (int j = 0; j < 4; j++)
      bfr[j] = *(const bf16x8*)&Bs[(wc * 64 + j * 16 + lo) * 32 + quad * 8];
#pragma unroll
    for (int i = 0; i < 4; i++)
#pragma unroll
      for (int j = 0; j < 4; j++)
        acc[i][j] = MFMA16(af[i], bfr[j], acc[i][j]);
  }
  if (z == 2) {
    // transposed V epilogue: Vt[((b*H+h)*DH + d)*S + s], 4 s-consecutive per lane
#pragma unroll
    for (int i = 0; i < 4; i++) {
      const int row0 = bn * 128 + wr * 64 + i * 16 + quad * 4;
      const int bb = row0 >> 11, s = row0 & (S_ - 1);
#pragma unroll
      for (int j = 0; j < 4; j++) {
        const int col = bm * 128 + wc * 64 + j * 16 + lo;
        const int hh = col >> 6, dd = col & 63;
        const float bv = bias[col];
        bf16x4 o;
#pragma unroll
        for (int r = 0; r < 4; r++) o[r] = (__bf16)(acc[i][j][r] + bv);
        *(bf16x4*)&C[((size_t)(bb * H_ + hh) * DH_ + dd) * S_ + s] = o;
      }
    }
  } else {
#pragma unroll
    for (int i = 0; i < 4; i++) {
      const int row = bn * 128 + wr * 64 + i * 16 + quad * 4;
#pragma unroll
      for (int j = 0; j < 4; j++) {
        const int col = bm * 128 + wc * 64 + j * 16 + lo;
        const float bv = bias[col];
#pragma unroll
        for (int r = 0; r < 4; r++)
          C[(size_t)(row + r) * D_ + col] = (__bf16)(acc[i][j][r] + bv);
      }
    }
  }
}

// ---------------------------------------------------------------------------
// Sliding-window attention v2. Block=(q-tile 64, h, b). All tiles staged via
// global_load_lds (16B) with XOR-swizzled segment order: LDS stride stays 64
// (required: dest is wave-uniform base + lane*16) but physical 16B-segment
// sp holds global segment sp^(row&7), making fragment ds_read_b128 2-way
// (free) instead of 16-way conflicted. Single-pass softmax in VGPRs.
__global__ __launch_bounds__(256, 2) void attn_win2(
    const __bf16* __restrict__ Qp, const __bf16* __restrict__ Kp,
    const __bf16* __restrict__ Vt, __bf16* __restrict__ ctx) {
  __shared__ __bf16 Qs[64 * 64];        //  8 KB
  __shared__ __bf16 Ks[5][64 * 64];     // 40 KB
  __shared__ __bf16 Vs[2][64 * 64];     // 16 KB  (Vt tiles: [d][s])
  __shared__ __bf16 Pb[4][16 * 72];     //  9 KB  (per-wave, stride 72)
  const int qt = blockIdx.x, h = blockIdx.y, b = blockIdx.z;
  const int q0 = qt * 64;
  const int tid = threadIdx.x, wave = tid >> 6, lane = tid & 63;
  const int lo = lane & 15, quad = lane >> 4;
  const int tmin = (q0 >= 256) ? 0 : ((256 - q0) >> 6);  // block-uniform
  const __bf16* Qg = Qp + ((size_t)b * S_ + q0) * D_ + h * DH_;
  const __bf16* Kg = Kp + (size_t)b * S_ * D_ + h * DH_;
  const __bf16* Vg = Vt + (size_t)(b * H_ + h) * DH_ * S_;

  const int c0 = tid, c1 = tid + 256;
  const int rA = c0 >> 3, gA = ((c0 & 7) ^ (rA & 7)) * 8;
  const int rB = c1 >> 3, gB = ((c1 & 7) ^ (rB & 7)) * 8;

  auto stageV = [&](int t) {  // k0 >= 0 guaranteed for t >= tmin
    const int k0 = q0 - 256 + t * 64;
    gload_lds16(Vg + (size_t)rA * S_ + k0 + gA, &Vs[t & 1][c0 * 8]);
    gload_lds16(Vg + (size_t)rB * S_ + k0 + gB, &Vs[t & 1][c1 * 8]);
  };

  // ---- stage Q, K[tmin..4], prefetch V[tmin], V[tmin+1]; ONE barrier ----
  gload_lds16(Qg + (size_t)rA * D_ + gA, &Qs[c0 * 8]);
  gload_lds16(Qg + (size_t)rB * D_ + gB, &Qs[c1 * 8]);
#pragma unroll
  for (int t = 0; t < 5; t++) {
    if (t < tmin) continue;
    const int k0 = q0 - 256 + t * 64;
    gload_lds16(Kg + (size_t)(k0 + rA) * D_ + gA, &Ks[t][c0 * 8]);
    gload_lds16(Kg + (size_t)(k0 + rB) * D_ + gB, &Ks[t][c1 * 8]);
  }
  stageV(tmin);
  if (tmin + 1 <= 4) stageV(tmin + 1);
  __syncthreads();

  // fragment read swizzle: logical seg g -> physical g^(row&7); row&7 == lo&7
  const int g0 = (quad ^ (lo & 7)) * 8;
  const int g1 = ((quad + 4) ^ (lo & 7)) * 8;

  // ---- scores ----
  const int qrow = wave * 16 + lo;
  const bf16x8 qf0 = *(const bf16x8*)&Qs[qrow * 64 + g0];
  const bf16x8 qf1 = *(const bf16x8*)&Qs[qrow * 64 + g1];
  f32x4 sc[5][4];
#pragma unroll
  for (int t = 0; t < 5; t++) {
    if (t < tmin) continue;
#pragma unroll
    for (int kt = 0; kt < 4; kt++) {
      const int kr = kt * 16 + lo;
      const bf16x8 kf0 = *(const bf16x8*)&Ks[t][kr * 64 + g0];
      const bf16x8 kf1 = *(const bf16x8*)&Ks[t][kr * 64 + g1];
      f32x4 c = {0.f, 0.f, 0.f, 0.f};
      c = MFMA16(qf0, kf0, c);
      c = MFMA16(qf1, kf1, c);
      sc[t][kt] = c;
    }
  }

  // ---- mask + softmax (C-layout: q=quad*4+r, k=kt*16+lo) ----
  const float scale = 0.125f;
  const int dbase = lo - wave * 16 - quad * 4 - 256;  // delta = kg - qg
  float mrow[4] = {-3e38f, -3e38f, -3e38f, -3e38f};
#pragma unroll
  for (int t = 0; t < 5; t++) {
    if (t < tmin) continue;
#pragma unroll
    for (int kt = 0; kt < 4; kt++)
#pragma unroll
      for (int r = 0; r < 4; r++) {
        const int delta = dbase + t * 64 + kt * 16 - r;
        const bool keep = (delta <= 0) && (delta > -256);
        const float v = keep ? sc[t][kt][r] * scale : -3e38f;
        sc[t][kt][r] = v;
        mrow[r] = fmaxf(mrow[r], v);
      }
  }
#pragma unroll
  for (int r = 0; r < 4; r++)
#pragma unroll
    for (int off = 1; off < 16; off <<= 1)
      mrow[r] = fmaxf(mrow[r], __shfl_xor(mrow[r], off));

  float lrow[4] = {0.f, 0.f, 0.f, 0.f};
#pragma unroll
  for (int t = 0; t < 5; t++) {
    if (t < tmin) continue;
#pragma unroll
    for (int kt = 0; kt < 4; kt++)
#pragma unroll
      for (int r = 0; r < 4; r++) {
        const float p = __expf(sc[t][kt][r] - mrow[r]);
        sc[t][kt][r] = p;
        lrow[r] += p;
      }
  }
#pragma unroll
  for (int r = 0; r < 4; r++)
#pragma unroll
    for (int off = 1; off < 16; off <<= 1)
      lrow[r] += __shfl_xor(lrow[r], off);

  // ---- O = P V. Pb is per-wave (same-wave RAW/WAR: DS in-order, no barrier).
  // V dbuf: one barrier per tile protects buffer reuse + drains stage(t+1).
  f32x4 oacc[4] = {};
#pragma unroll
  for (int t = 0; t < 5; t++) {
    if (t < tmin) continue;
#pragma unroll
    for (int kt = 0; kt < 4; kt++)
#pragma unroll
      for (int r = 0; r < 4; r++)
        Pb[wave][(quad * 4 + r) * 72 + kt * 16 + lo] = (__bf16)sc[t][kt][r];
    const bf16x8 pf0 = *(const bf16x8*)&Pb[wave][lo * 72 + quad * 8];
    const bf16x8 pf1 = *(const bf16x8*)&Pb[wave][lo * 72 + 32 + quad * 8];
#pragma unroll
    for (int ds = 0; ds < 4; ds++) {
      const bf16x8 vf0 = *(const bf16x8*)&Vs[t & 1][(ds * 16 + lo) * 64 + g0];
      const bf16x8 vf1 = *(const bf16x8*)&Vs[t & 1][(ds * 16 + lo) * 64 + g1];
      oacc[ds] = MFMA16(pf0, vf0, oacc[ds]);
      oacc[ds] = MFMA16(pf1, vf1, oacc[ds]);
    }
    if (t < 4) {
      __syncthreads();
      if (t + 2 <= 4) stageV(t + 2);  // into buf t&1, just freed
    }
  }

  // ---- write ctx ----
#pragma unroll
  for (int ds = 0; ds < 4; ds++)
#pragma unroll
    for (int r = 0; r < 4; r++) {
      const int qg = q0 + wave * 16 + quad * 4 + r;
      ctx[((size_t)b * S_ + qg) * D_ + h * DH_ + ds * 16 + lo] =
          (__bf16)(oacc[ds][r] / lrow[r]);
    }
}

// ---------------------------------------------------------------------------
// Output projection: 64x128 tile (512 blocks -> 2/CU), fp32 out.
__global__ __launch_bounds__(256, 2) void gemm_o(
    const __bf16* __restrict__ A, const __bf16* __restrict__ W,
    const float* __restrict__ bias, float* __restrict__ C) {
  __shared__ __bf16 As[64 * 32];    // 4 KB
  __shared__ __bf16 Bs[128 * 32];   // 8 KB
  const int tid = threadIdx.x, lane = tid & 63, wave = tid >> 6;
  const int lo = lane & 15, quad = lane >> 4;
  const int wr = wave & 1, wc = wave >> 1;
  const int bn = blockIdx.x, bm = blockIdx.y;
  const __bf16* Ag = A + (size_t)bn * 64 * D_;
  const __bf16* Wg = W + (size_t)bm * 128 * D_;
  const int ra = tid >> 2, sa = (tid & 3) * 8;
  const int cb0 = tid, cb1 = tid + 256;
  const int rb0 = cb0 >> 2, sb0 = (cb0 & 3) * 8;
  const int rb1 = cb1 >> 2, sb1 = (cb1 & 3) * 8;
  f32x4 acc[2][4] = {};
  for (int k0 = 0; k0 < D_; k0 += 32) {
    __syncthreads();
    gload_lds16(Ag + (size_t)ra * D_ + k0 + sa, &As[tid * 8]);
    gload_lds16(Wg + (size_t)rb0 * D_ + k0 + sb0, &Bs[cb0 * 8]);
    gload_lds16(Wg + (size_t)rb1 * D_ + k0 + sb1, &Bs[cb1 * 8]);
    __syncthreads();
    bf16x8 af[2], bfr[4];
#pragma unroll
    for (int i = 0; i < 2; i++)
      af[i] = *(const bf16x8*)&As[(wr * 32 + i * 16 + lo) * 32 + quad * 8];
#pragma unroll
    for (int j = 0; j < 4; j++)
      bfr[j] = *(const bf16x8*)&Bs[(wc * 64 + j * 16 + lo) * 32 + quad * 8];
#pragma unroll
    for (int i = 0; i < 2; i++)
#pragma unroll
      for (int j = 0; j < 4; j++)
        acc[i][j] = MFMA16(af[i], bfr[j], acc[i][j]);
  }
#pragma unroll
  for (int i = 0; i < 2; i++) {
    const int row = bn * 64 + wr * 32 + i * 16 + quad * 4;
#pragma unroll
    for (int j = 0; j < 4; j++) {
      const int col = bm * 128 + wc * 64 + j * 16 + lo;
      const float bv = bias[col];
#pragma unroll
      for (int r = 0; r < 4; r++)
        C[(size_t)(row + r) * D_ + col] = acc[i][j][r] + bv;
    }
  }
}

// ---------------------------------------------------------------------------
extern "C" void kernel_launch(void* const* d_in, const int* in_sizes, int n_in,
                              void* d_out, int out_size, void* d_ws, size_t ws_size,
                              hipStream_t stream) {
  (void)in_sizes; (void)n_in; (void)out_size; (void)ws_size;
  const float* q_in = (const float*)d_in[0];
  const float* k_in = (const float*)d_in[1];
  const float* v_in = (const float*)d_in[2];
  const float* Wq   = (const float*)d_in[3];
  const float* bq   = (const float*)d_in[4];
  const float* Wk   = (const float*)d_in[5];
  const float* bk   = (const float*)d_in[6];
  const float* Wv   = (const float*)d_in[7];
  const float* bv   = (const float*)d_in[8];
  const float* Wo   = (const float*)d_in[9];
  const float* bo   = (const float*)d_in[10];

  const size_t XN = (size_t)NROW * D_;  // 4M elems
  const size_t WN = (size_t)D_ * D_;    // 1M elems
  char* ws = (char*)d_ws;               // 64 MB total
  __bf16* xq  = (__bf16*)ws; ws += XN * 2;
  __bf16* xk  = (__bf16*)ws; ws += XN * 2;
  __bf16* xv  = (__bf16*)ws; ws += XN * 2;
  __bf16* wqb = (__bf16*)ws; ws += WN * 2;
  __bf16* wkb = (__bf16*)ws; ws += WN * 2;
  __bf16* wvb = (__bf16*)ws; ws += WN * 2;
  __bf16* wob = (__bf16*)ws; ws += WN * 2;
  __bf16* Qp  = (__bf16*)ws; ws += XN * 2;
  __bf16* Kp  = (__bf16*)ws; ws += XN * 2;
  __bf16* Vtp = (__bf16*)ws; ws += XN * 2;  // [B][H][DH][S]
  __bf16* ctx = (__bf16*)ws; ws += XN * 2;

  Ptr3 xs{{q_in, k_in, v_in}};
  Ptr4 wsrc{{Wq, Wk, Wv, Wo}};
  cast3<<<dim3((int)(XN / 4 / 256), 3), 256, 0, stream>>>(xs, xq, (int)(XN / 4));
  cast4<<<dim3((int)(WN / 4 / 256), 4), 256, 0, stream>>>(wsrc, wqb, (int)(WN / 4));

  QKVArgs qa;
  qa.A[0] = xq;  qa.A[1] = xk;  qa.A[2] = xv;
  qa.W[0] = wqb; qa.W[1] = wkb; qa.W[2] = wvb;
  qa.bias[0] = bq; qa.bias[1] = bk; qa.bias[2] = bv;
  qa.C[0] = Qp; qa.C[1] = Kp; qa.C[2] = Vtp;
  gemm_qkv<<<dim3(NROW / 128, D_ / 128, 3), 256, 0, stream>>>(qa);

  attn_win2<<<dim3(S_ / 64, H_, B_), 256, 0, stream>>>(Qp, Kp, Vtp, ctx);

  gemm_o<<<dim3(NROW / 64, D_ / 128), 256, 0, stream>>>(ctx, wob, bo, (float*)d_out);
}